// Round 5
// baseline (459.970 us; speedup 1.0000x reference)
//
#include <hip/hip_runtime.h>
#include <hip/hip_bf16.h>
#include <stdint.h>

#define N 4096

typedef __attribute__((ext_vector_type(4))) float f32x4;
typedef __attribute__((ext_vector_type(8))) short s16x8;   // 8 bf16 lanes (4 VGPRs)

__device__ inline unsigned short f2bf(float f) {
    unsigned int u = __float_as_uint(f);
    u += 0x7fffu + ((u >> 16) & 1u);        // RNE
    return (unsigned short)(u >> 16);
}
__device__ inline float bf2f(unsigned short h) {
    return __uint_as_float(((unsigned int)h) << 16);
}

// ---------------- k0a: T = w3@w2 [64][256] per graph, b_eff = w3@(w2@b1+b2)+b3 ----------------
__global__ void k0a(const float* __restrict__ w2a, const float* __restrict__ w3a,
                    const float* __restrict__ b1a, const float* __restrict__ b2a, const float* __restrict__ b3a,
                    const float* __restrict__ w2b, const float* __restrict__ w3b,
                    const float* __restrict__ b1b, const float* __restrict__ b2b, const float* __restrict__ b3b,
                    float* __restrict__ T, float* __restrict__ beff) {
    const int g  = blockIdx.x >> 5;
    const int nb = blockIdx.x & 31;
    const float* w2 = g ? w2b : w2a;   // [128][256]
    const float* w3 = g ? w3b : w3a;   // [64][128]
    const int c  = threadIdx.x;
    const int n0 = nb * 2;
    float a0 = 0.f, a1 = 0.f;
#pragma unroll 8
    for (int r = 0; r < 128; ++r) {
        float w = w2[r * 256 + c];
        a0 += w3[n0 * 128 + r] * w;            // block-uniform -> s_load
        a1 += w3[n0 * 128 + 128 + r] * w;
    }
    float* Tg = T + g * 64 * 256;
    Tg[n0 * 256 + c]       = a0;
    Tg[(n0 + 1) * 256 + c] = a1;

    if (nb == 0) {                              // bias path (biases zero in setup; compute anyway)
        __shared__ float u[128];
        const float* b1 = g ? b1b : b1a;
        const float* b2 = g ? b2b : b2a;
        const float* b3 = g ? b3b : b3a;
        if (threadIdx.x < 128) {
            int r = threadIdx.x;
            float s = 0.f;
            for (int cc = 0; cc < 256; ++cc) s += w2[r * 256 + cc] * b1[cc];
            u[r] = s + b2[r];
        }
        __syncthreads();
        if (threadIdx.x < 64) {
            int n = threadIdx.x;
            float s = 0.f;
            for (int r = 0; r < 128; ++r) s += w3[n * 128 + r] * u[r];
            beff[g * 64 + n] = s + b3[n];
        }
    }
}

// ---------------- k0b: Weff = T@w1, emitted directly in MFMA fragment layout (hi/lo planes) ----
// Wfrag unit (1 KB = 64 lanes x 16 B): unit = (((g*64+kc)*4+ng)*2+c)*2 + pl
// lane (q,l15) of fragment (kc,c) holds Weff[n=ng*16+l15][k=kc*64+c*32+q*8 .. +7]
__global__ __launch_bounds__(256) void k0b(const float* __restrict__ w1a, const float* __restrict__ w1b,
                                           const float* __restrict__ T,
                                           unsigned short* __restrict__ Wfrag) {
    const int b  = blockIdx.x;
    const int g  = b >> 6, kc = b & 63;
    const float* w1 = g ? w1b : w1a;                  // [256][4096]
    const int t = threadIdx.x;
    const int ng = t >> 6, lane = t & 63;
    const int q = lane >> 4, l15 = lane & 15;
    const float* Trow = T + (size_t)(g * 64 + ng * 16 + l15) * 256;
    const int kx0 = kc * 64 + q * 8;

    float acc[2][8];
#pragma unroll
    for (int c = 0; c < 2; ++c)
#pragma unroll
        for (int j = 0; j < 8; ++j) acc[c][j] = 0.f;

#pragma unroll 4
    for (int r = 0; r < 256; ++r) {
        float tv = Trow[r];
        const float* wr = w1 + (size_t)r * N + kx0;
        float4 wa = *(const float4*)&wr[0];
        float4 wb = *(const float4*)&wr[4];
        float4 wc = *(const float4*)&wr[32];
        float4 wd = *(const float4*)&wr[36];
        acc[0][0] += tv * wa.x; acc[0][1] += tv * wa.y; acc[0][2] += tv * wa.z; acc[0][3] += tv * wa.w;
        acc[0][4] += tv * wb.x; acc[0][5] += tv * wb.y; acc[0][6] += tv * wb.z; acc[0][7] += tv * wb.w;
        acc[1][0] += tv * wc.x; acc[1][1] += tv * wc.y; acc[1][2] += tv * wc.z; acc[1][3] += tv * wc.w;
        acc[1][4] += tv * wd.x; acc[1][5] += tv * wd.y; acc[1][6] += tv * wd.z; acc[1][7] += tv * wd.w;
    }

#pragma unroll
    for (int c = 0; c < 2; ++c) {
        unsigned short hi[8], lo[8];
#pragma unroll
        for (int j = 0; j < 8; ++j) {
            hi[j] = f2bf(acc[c][j]);
            lo[j] = f2bf(acc[c][j] - bf2f(hi[j]));
        }
        const size_t unit = ((((size_t)g * 64 + kc) * 4 + ng) * 2 + c) * 2;
        uint4 hp, lp;
        hp.x = (unsigned)hi[0] | ((unsigned)hi[1] << 16); hp.y = (unsigned)hi[2] | ((unsigned)hi[3] << 16);
        hp.z = (unsigned)hi[4] | ((unsigned)hi[5] << 16); hp.w = (unsigned)hi[6] | ((unsigned)hi[7] << 16);
        lp.x = (unsigned)lo[0] | ((unsigned)lo[1] << 16); lp.y = (unsigned)lo[2] | ((unsigned)lo[3] << 16);
        lp.z = (unsigned)lo[4] | ((unsigned)lo[5] << 16); lp.w = (unsigned)lo[6] | ((unsigned)lo[7] << 16);
        *(uint4*)&Wfrag[unit * 512 + lane * 8]       = hp;
        *(uint4*)&Wfrag[(unit + 1) * 512 + lane * 8] = lp;
    }
}

// ---------------- k1: h = relu(x @ Weff.T + beff), split-bf16; 8 K-group waves; frag B loads ----
// hfrag unit: ((g*4+ng)*64 + jc)*2 + c ; lane (q,l15) holds h[j=jc*64+c*32+q*8..+7][n=ng*16+l15]
__global__ __launch_bounds__(512, 4) void k1(const float* __restrict__ x1, const float* __restrict__ x2,
                                             const unsigned short* __restrict__ Wfrag,
                                             const float* __restrict__ beff,
                                             float* __restrict__ hf, unsigned short* __restrict__ hfrag) {
    const int b  = blockIdx.x;
    const int g  = b & 1;
    const int i0 = (b >> 1) * 16;
    const float* x = g ? x2 : x1;

    const int t = threadIdx.x;
    const int lane = t & 63, kg = t >> 6;           // 8 waves = 8 K-groups of 512
    const int q = lane >> 4, l15 = lane & 15;

    __shared__ float accs[8][4][64][4];             // 32 KB
    __shared__ unsigned short htile[64][16];        // 2 KB  [n][ilocal]

    f32x4 acc[4];
#pragma unroll
    for (int ng = 0; ng < 4; ++ng) acc[ng] = (f32x4){0.f, 0.f, 0.f, 0.f};

    const float* xrow = x + (size_t)(i0 + l15) * N;
    for (int kk = 0; kk < 8; ++kk) {
        const int kc = kg * 8 + kk;
#pragma unroll
        for (int c = 0; c < 2; ++c) {
            const int ka = kc * 64 + c * 32 + q * 8;
            float4 a0 = *(const float4*)&xrow[ka];
            float4 a1 = *(const float4*)&xrow[ka + 4];
            s16x8 bh[4], bl[4];
#pragma unroll
            for (int ng = 0; ng < 4; ++ng) {
                const size_t unit = ((((size_t)g * 64 + kc) * 4 + ng) * 2 + c) * 2;
                bh[ng] = *(const s16x8*)&Wfrag[unit * 512 + lane * 8];
                bl[ng] = *(const s16x8*)&Wfrag[(unit + 1) * 512 + lane * 8];
            }
            float xv[8] = {a0.x, a0.y, a0.z, a0.w, a1.x, a1.y, a1.z, a1.w};
            s16x8 ah, al;
#pragma unroll
            for (int j = 0; j < 8; ++j) {
                unsigned short h = f2bf(xv[j]);
                ah[j] = (short)h;
                al[j] = (short)f2bf(xv[j] - bf2f(h));
            }
#pragma unroll
            for (int ng = 0; ng < 4; ++ng) {
                acc[ng] = __builtin_amdgcn_mfma_f32_16x16x32_bf16(al, bh[ng], acc[ng], 0, 0, 0);
                acc[ng] = __builtin_amdgcn_mfma_f32_16x16x32_bf16(ah, bl[ng], acc[ng], 0, 0, 0);
                acc[ng] = __builtin_amdgcn_mfma_f32_16x16x32_bf16(ah, bh[ng], acc[ng], 0, 0, 0);
            }
        }
    }
#pragma unroll
    for (int ng = 0; ng < 4; ++ng)
#pragma unroll
        for (int r = 0; r < 4; ++r) accs[kg][ng][lane][r] = acc[ng][r];
    __syncthreads();

    // wave (ng = kg&3, r-half = kg>>2) reduces over the 8 K-groups
    {
        const int ng = kg & 3, rh = kg >> 2;
        const int n = ng * 16 + l15;
        const float be = beff[g * 64 + n];
#pragma unroll
        for (int rr = 0; rr < 2; ++rr) {
            const int r = rh * 2 + rr;
            float s = 0.f;
#pragma unroll
            for (int k8 = 0; k8 < 8; ++k8) s += accs[k8][ng][lane][r];
            float v = fmaxf(s + be, 0.f);
            const int il = q * 4 + r;
            hf[(size_t)(g * N + i0 + il) * 64 + n] = v;
            htile[n][il] = f2bf(v);
        }
    }
    __syncthreads();

    if (t < 128) {                                  // emit hfrag (contiguous 16 B per thread)
        const int ng2 = t >> 5, jh = (t >> 4) & 1, l = t & 15;
        uint4 v = *(const uint4*)&htile[ng2 * 16 + l][jh * 8];
        const int jc = i0 >> 6, c = (i0 >> 5) & 1, q0 = (i0 >> 3) & 3;
        const size_t unit = (((size_t)g * 4 + ng2) * 64 + jc) * 2 + c;
        *(uint4*)&hfrag[unit * 512 + (size_t)(q0 + jh) * 128 + l * 8] = v;
    }
}

// ---------------- k2: agg = (adj==1)*alpha @ h; A = prepacked hfrag, B = masked alpha --------
__global__ __launch_bounds__(512, 2) void k2(const int* __restrict__ adj1, const int* __restrict__ adj2,
                                             const float* __restrict__ alpha, const float* __restrict__ Wp,
                                             const unsigned short* __restrict__ hfrag,
                                             const float* __restrict__ hf,
                                             float* __restrict__ outv) {
    const int i0 = blockIdx.x * 16;
    const int t = threadIdx.x;
    const int lane = t & 63, kg = t >> 6;           // 8 waves = 8 K-groups of 512
    const int q = lane >> 4, l15 = lane & 15;

    __shared__ float accs[8][4][64][4];             // 32 KB (reused for graph1 then graph2)
    __shared__ float degp[8][64][2];                // 4 KB
    __shared__ float degf[2][16];

    f32x4 acc1[4], acc2[4];
#pragma unroll
    for (int ng = 0; ng < 4; ++ng) {
        acc1[ng] = (f32x4){0.f, 0.f, 0.f, 0.f};
        acc2[ng] = (f32x4){0.f, 0.f, 0.f, 0.f};
    }
    int deg1 = 0, deg2 = 0;

    const size_t rowoff = (size_t)(i0 + l15) * N;
    for (int kk = 0; kk < 8; ++kk) {
        const int jc = kg * 8 + kk;
#pragma unroll
        for (int c = 0; c < 2; ++c) {
            const int ka = jc * 64 + c * 32 + q * 8;
            const size_t ao = rowoff + ka;
            float4 a0 = *(const float4*)&alpha[ao];
            float4 a1 = *(const float4*)&alpha[ao + 4];
            int4 j10 = *(const int4*)&adj1[ao];
            int4 j11 = *(const int4*)&adj1[ao + 4];
            int4 j20 = *(const int4*)&adj2[ao];
            int4 j21 = *(const int4*)&adj2[ao + 4];
            s16x8 ha1[4], ha2[4];
#pragma unroll
            for (int ng = 0; ng < 4; ++ng) {
                const size_t u1 = (((size_t)0 * 4 + ng) * 64 + jc) * 2 + c;
                const size_t u2 = (((size_t)1 * 4 + ng) * 64 + jc) * 2 + c;
                ha1[ng] = *(const s16x8*)&hfrag[u1 * 512 + lane * 8];
                ha2[ng] = *(const s16x8*)&hfrag[u2 * 512 + lane * 8];
            }
            float av[8] = {a0.x, a0.y, a0.z, a0.w, a1.x, a1.y, a1.z, a1.w};
            int m1[8] = {j10.x == 1, j10.y == 1, j10.z == 1, j10.w == 1,
                         j11.x == 1, j11.y == 1, j11.z == 1, j11.w == 1};
            int m2[8] = {j20.x == 1, j20.y == 1, j20.z == 1, j20.w == 1,
                         j21.x == 1, j21.y == 1, j21.z == 1, j21.w == 1};
            s16x8 bf1, bf2;
#pragma unroll
            for (int j = 0; j < 8; ++j) {
                short bv = (short)f2bf(av[j]);
                bf1[j] = m1[j] ? bv : (short)0;
                bf2[j] = m2[j] ? bv : (short)0;
                deg1 += m1[j];
                deg2 += m2[j];
            }
#pragma unroll
            for (int ng = 0; ng < 4; ++ng) {
                acc1[ng] = __builtin_amdgcn_mfma_f32_16x16x32_bf16(ha1[ng], bf1, acc1[ng], 0, 0, 0);
                acc2[ng] = __builtin_amdgcn_mfma_f32_16x16x32_bf16(ha2[ng], bf2, acc2[ng], 0, 0, 0);
            }
        }
    }

    degp[kg][lane][0] = (float)deg1;
    degp[kg][lane][1] = (float)deg2;
#pragma unroll
    for (int ng = 0; ng < 4; ++ng)
#pragma unroll
        for (int r = 0; r < 4; ++r) accs[kg][ng][lane][r] = acc1[ng][r];
    __syncthreads();
    if (t < 32) {                                   // deg: sum over 8 kg x 4 q slices
        int gg = t >> 4, row = t & 15;
        float s = 0.f;
#pragma unroll
        for (int w = 0; w < 8; ++w)
#pragma unroll
            for (int qq = 0; qq < 4; ++qq) s += degp[w][qq * 16 + row][gg];
        degf[gg][row] = s;
    }
    __syncthreads();

    const float W00 = Wp[0];
    {   // graph 1 epilogue: lane holds (n = ng*16+q*4+r, i = i0+l15)
        const int ng = kg & 3, rh = kg >> 2;
        const int i = i0 + l15;
        const float dg = degf[0][l15];
#pragma unroll
        for (int rr = 0; rr < 2; ++rr) {
            const int r = rh * 2 + rr;
            float s = 0.f;
#pragma unroll
            for (int k8 = 0; k8 < 8; ++k8) s += accs[k8][ng][lane][r];
            const int n = ng * 16 + q * 4 + r;
            float hv = hf[(size_t)i * 64 + n];
            outv[(size_t)i * 64 + n] = (dg != 0.f) ? (s * W00 / fmaxf(dg, 1.f) + hv) : 0.f;
        }
    }
    __syncthreads();                                // done reading accs (graph1)
#pragma unroll
    for (int ng = 0; ng < 4; ++ng)
#pragma unroll
        for (int r = 0; r < 4; ++r) accs[kg][ng][lane][r] = acc2[ng][r];
    __syncthreads();
    {   // graph 2 epilogue
        const int ng = kg & 3, rh = kg >> 2;
        const int i = i0 + l15;
        const float dg = degf[1][l15];
#pragma unroll
        for (int rr = 0; rr < 2; ++rr) {
            const int r = rh * 2 + rr;
            float s = 0.f;
#pragma unroll
            for (int k8 = 0; k8 < 8; ++k8) s += accs[k8][ng][lane][r];
            const int n = ng * 16 + q * 4 + r;
            float hv = hf[(size_t)(N + i) * 64 + n];
            outv[(size_t)(N + i) * 64 + n] = (dg != 0.f) ? (s * W00 / fmaxf(dg, 1.f) + hv) : 0.f;
        }
    }
}

// ---------------- k3a/k3b: out = feat @ clf_w.T + clf_b (two-stage deterministic reduction) ----------------
__global__ __launch_bounds__(256) void k3a(const float* __restrict__ feat, const float* __restrict__ clfw,
                                           float* __restrict__ part) {
    const int t = threadIdx.x;
    const size_t idx = (size_t)blockIdx.x * 2048 + (size_t)t * 8;
    float4 a0 = *(const float4*)&feat[idx];
    float4 a1 = *(const float4*)&feat[idx + 4];
    float4 c0 = *(const float4*)&clfw[idx];
    float4 c1 = *(const float4*)&clfw[idx + 4];
    float4 d0 = *(const float4*)&clfw[524288 + idx];
    float4 d1 = *(const float4*)&clfw[524288 + idx + 4];
    float s0 = a0.x * c0.x + a0.y * c0.y + a0.z * c0.z + a0.w * c0.w
             + a1.x * c1.x + a1.y * c1.y + a1.z * c1.z + a1.w * c1.w;
    float s1 = a0.x * d0.x + a0.y * d0.y + a0.z * d0.z + a0.w * d0.w
             + a1.x * d1.x + a1.y * d1.y + a1.z * d1.z + a1.w * d1.w;
    __shared__ float r0[256], r1[256];
    r0[t] = s0; r1[t] = s1;
    __syncthreads();
    for (int s = 128; s > 0; s >>= 1) {
        if (t < s) { r0[t] += r0[t + s]; r1[t] += r1[t + s]; }
        __syncthreads();
    }
    if (t == 0) { part[blockIdx.x * 2] = r0[0]; part[blockIdx.x * 2 + 1] = r1[0]; }
}

__global__ void k3b(const float* __restrict__ part, const float* __restrict__ clfb,
                    float* __restrict__ outp) {
    const int t = threadIdx.x;
    __shared__ float r0[256], r1[256];
    r0[t] = part[t * 2]; r1[t] = part[t * 2 + 1];
    __syncthreads();
    for (int s = 128; s > 0; s >>= 1) {
        if (t < s) { r0[t] += r0[t + s]; r1[t] += r1[t + s]; }
        __syncthreads();
    }
    if (t == 0) { outp[0] = r0[0] + clfb[0]; outp[1] = r1[0] + clfb[1]; }
}

extern "C" void kernel_launch(void* const* d_in, const int* in_sizes, int n_in,
                              void* d_out, int out_size, void* d_ws, size_t ws_size,
                              hipStream_t stream) {
    const float* x1   = (const float*)d_in[0];
    const float* x2   = (const float*)d_in[1];
    const int*   adj1 = (const int*)d_in[2];
    const int*   adj2 = (const int*)d_in[3];
    const float* e1w1 = (const float*)d_in[4];
    const float* e1b1 = (const float*)d_in[5];
    const float* e1w2 = (const float*)d_in[6];
    const float* e1b2 = (const float*)d_in[7];
    const float* e1w3 = (const float*)d_in[8];
    const float* e1b3 = (const float*)d_in[9];
    const float* e2w1 = (const float*)d_in[10];
    const float* e2b1 = (const float*)d_in[11];
    const float* e2w2 = (const float*)d_in[12];
    const float* e2b2 = (const float*)d_in[13];
    const float* e2w3 = (const float*)d_in[14];
    const float* e2b3 = (const float*)d_in[15];
    const float* Wp   = (const float*)d_in[16];
    const float* alph = (const float*)d_in[17];
    const float* clfw = (const float*)d_in[18];
    const float* clfb = (const float*)d_in[19];

    char* wsb = (char*)d_ws;
    // Wfrag (2 MB) lives through k1; newv (2 MB) aliases it from k2 on.
    unsigned short* Wfrag = (unsigned short*)(wsb);                      // 2 MB
    float* newv = (float*)(wsb);                                         // 2 MB (aliases Wfrag)
    unsigned short* hfrag = (unsigned short*)(wsb + (2u << 20));         // 1 MB
    float* hf   = (float*)(wsb + (3u << 20));                            // 2 MB
    float* T    = (float*)(wsb + (5u << 20));                            // 128 KB
    float* beff = (float*)(wsb + (5u << 20) + (1u << 17));               // 512 B
    float* part = (float*)(wsb + (5u << 20) + (1u << 17) + 4096);        // 2 KB

    hipLaunchKernelGGL(k0a, dim3(64), dim3(256), 0, stream,
                       e1w2, e1w3, e1b1, e1b2, e1b3, e2w2, e2w3, e2b1, e2b2, e2b3, T, beff);
    hipLaunchKernelGGL(k0b, dim3(128), dim3(256), 0, stream, e1w1, e2w1, T, Wfrag);
    hipLaunchKernelGGL(k1, dim3(512), dim3(512), 0, stream, x1, x2, Wfrag, beff, hf, hfrag);
    hipLaunchKernelGGL(k2, dim3(256), dim3(512), 0, stream, adj1, adj2, alph, Wp, hfrag, hf, newv);
    hipLaunchKernelGGL(k3a, dim3(256), dim3(256), 0, stream, newv, clfw, part);
    hipLaunchKernelGGL(k3b, dim3(1), dim3(256), 0, stream, part, clfb, (float*)d_out);
}

// Round 6
// 402.522 us; speedup vs baseline: 1.1427x; 1.1427x over previous
//
#include <hip/hip_runtime.h>
#include <hip/hip_bf16.h>
#include <stdint.h>

#define N 4096

typedef __attribute__((ext_vector_type(4))) float f32x4;
typedef __attribute__((ext_vector_type(8))) short s16x8;   // 8 bf16 lanes (4 VGPRs)

__device__ inline unsigned short f2bf(float f) {
    unsigned int u = __float_as_uint(f);
    u += 0x7fffu + ((u >> 16) & 1u);        // RNE
    return (unsigned short)(u >> 16);
}
__device__ inline float bf2f(unsigned short h) {
    return __uint_as_float(((unsigned int)h) << 16);
}

// ---------------- k0a: T = w3@w2 [64][256] per graph, b_eff = w3@(w2@b1+b2)+b3 ----------------
__global__ void k0a(const float* __restrict__ w2a, const float* __restrict__ w3a,
                    const float* __restrict__ b1a, const float* __restrict__ b2a, const float* __restrict__ b3a,
                    const float* __restrict__ w2b, const float* __restrict__ w3b,
                    const float* __restrict__ b1b, const float* __restrict__ b2b, const float* __restrict__ b3b,
                    float* __restrict__ T, float* __restrict__ beff) {
    const int g  = blockIdx.x >> 5;
    const int nb = blockIdx.x & 31;
    const float* w2 = g ? w2b : w2a;   // [128][256]
    const float* w3 = g ? w3b : w3a;   // [64][128]
    const int c  = threadIdx.x;
    const int n0 = nb * 2;
    float a0 = 0.f, a1 = 0.f;
#pragma unroll 8
    for (int r = 0; r < 128; ++r) {
        float w = w2[r * 256 + c];
        a0 += w3[n0 * 128 + r] * w;            // block-uniform -> s_load
        a1 += w3[n0 * 128 + 128 + r] * w;
    }
    float* Tg = T + g * 64 * 256;
    Tg[n0 * 256 + c]       = a0;
    Tg[(n0 + 1) * 256 + c] = a1;

    if (nb == 0) {                              // bias path, parallelized (biases zero in setup; compute anyway)
        __shared__ float ps[256];
        __shared__ float u[128];
        const float* b1 = g ? b1b : b1a;
        const float* b2 = g ? b2b : b2a;
        const float* b3 = g ? b3b : b3a;
        {   // stage 1: u[r] = w2[r,:]·b1 + b2[r], split 2 ways per r
            const int r = threadIdx.x >> 1, half = threadIdx.x & 1;
            float s = 0.f;
#pragma unroll 8
            for (int cc = 0; cc < 128; ++cc) s += w2[r * 256 + half * 128 + cc] * b1[half * 128 + cc];
            ps[threadIdx.x] = s;
        }
        __syncthreads();
        if (threadIdx.x < 128)
            u[threadIdx.x] = ps[2 * threadIdx.x] + ps[2 * threadIdx.x + 1] + b2[threadIdx.x];
        __syncthreads();
        {   // stage 2: beff[n] = w3[n,:]·u + b3[n], split 4 ways per n
            const int n = threadIdx.x >> 2, qr = threadIdx.x & 3;
            float s = 0.f;
#pragma unroll
            for (int r = 0; r < 32; ++r) s += w3[n * 128 + qr * 32 + r] * u[qr * 32 + r];
            ps[threadIdx.x] = s;
        }
        __syncthreads();
        if (threadIdx.x < 64)
            beff[g * 64 + threadIdx.x] = ps[4 * threadIdx.x] + ps[4 * threadIdx.x + 1]
                                       + ps[4 * threadIdx.x + 2] + ps[4 * threadIdx.x + 3] + b3[threadIdx.x];
    }
}

// ---------------- k0b: Weff = T@w1 -> Wfrag (MFMA fragment layout, hi/lo planes) ----------------
// Coalesced w1 streams + block-uniform T rows (s_load). 512 blocks for latency hiding.
// Wfrag unit (1 KB): unit = (((g*64+kc)*4+ng)*2+c)*2 + pl ; lane(q,l15) holds
// Weff[n=ng*16+l15][k=kc*64+c*32+q*8 .. +7]
__global__ __launch_bounds__(256) void k0b(const float* __restrict__ w1a, const float* __restrict__ w1b,
                                           const float* __restrict__ T,
                                           unsigned short* __restrict__ Wfrag) {
    const int b  = blockIdx.x;                        // ((g*16 + n4)*16 + kchunk)
    const int g = b >> 8, n4 = (b >> 4) & 15, kchunk = b & 15;
    const float* w1 = g ? w1b : w1a;                  // [256][4096]
    const int kx = kchunk * 256 + threadIdx.x;
    const float* Tg = T + (size_t)(g * 64 + n4 * 4) * 256;   // block-uniform rows -> s_load
    float acc[4] = {0.f, 0.f, 0.f, 0.f};
#pragma unroll 8
    for (int r = 0; r < 256; ++r) {
        float w = w1[(size_t)r * N + kx];
#pragma unroll
        for (int j = 0; j < 4; ++j) acc[j] += Tg[j * 256 + r] * w;
    }
    const int kc = kx >> 6, cc = (kx >> 5) & 1, q = (kx >> 3) & 3, ko = kx & 7;
#pragma unroll
    for (int j = 0; j < 4; ++j) {
        const int n = n4 * 4 + j;
        const int ng = n >> 4, l15 = n & 15;
        const int lane = q * 16 + l15;
        const unsigned short hi = f2bf(acc[j]);
        const unsigned short lo = f2bf(acc[j] - bf2f(hi));
        const size_t unit = ((((size_t)g * 64 + kc) * 4 + ng) * 2 + cc) * 2;
        Wfrag[unit * 512 + lane * 8 + ko]       = hi;
        Wfrag[(unit + 1) * 512 + lane * 8 + ko] = lo;
    }
}

// ---------------- k1: h = relu(x @ Weff.T + beff), split-bf16; 8 K-group waves; frag B loads ----
// hfrag unit: ((g*4+ng)*64 + jc)*2 + c ; lane (q,l15) holds h[j=jc*64+c*32+q*8..+7][n=ng*16+l15]
__global__ __launch_bounds__(512, 4) void k1(const float* __restrict__ x1, const float* __restrict__ x2,
                                             const unsigned short* __restrict__ Wfrag,
                                             const float* __restrict__ beff,
                                             float* __restrict__ hf, unsigned short* __restrict__ hfrag) {
    const int b  = blockIdx.x;
    const int g  = b & 1;
    const int i0 = (b >> 1) * 16;
    const float* x = g ? x2 : x1;

    const int t = threadIdx.x;
    const int lane = t & 63, kg = t >> 6;           // 8 waves = 8 K-groups of 512
    const int q = lane >> 4, l15 = lane & 15;

    __shared__ float accs[8][4][64][4];             // 32 KB
    __shared__ unsigned short htile[64][16];        // 2 KB  [n][ilocal]

    f32x4 acc[4];
#pragma unroll
    for (int ng = 0; ng < 4; ++ng) acc[ng] = (f32x4){0.f, 0.f, 0.f, 0.f};

    const float* xrow = x + (size_t)(i0 + l15) * N;
    for (int kk = 0; kk < 8; ++kk) {
        const int kc = kg * 8 + kk;
#pragma unroll
        for (int c = 0; c < 2; ++c) {
            const int ka = kc * 64 + c * 32 + q * 8;
            float4 a0 = *(const float4*)&xrow[ka];
            float4 a1 = *(const float4*)&xrow[ka + 4];
            s16x8 bh[4], bl[4];
#pragma unroll
            for (int ng = 0; ng < 4; ++ng) {
                const size_t unit = ((((size_t)g * 64 + kc) * 4 + ng) * 2 + c) * 2;
                bh[ng] = *(const s16x8*)&Wfrag[unit * 512 + lane * 8];
                bl[ng] = *(const s16x8*)&Wfrag[(unit + 1) * 512 + lane * 8];
            }
            float xv[8] = {a0.x, a0.y, a0.z, a0.w, a1.x, a1.y, a1.z, a1.w};
            s16x8 ah, al;
#pragma unroll
            for (int j = 0; j < 8; ++j) {
                unsigned short h = f2bf(xv[j]);
                ah[j] = (short)h;
                al[j] = (short)f2bf(xv[j] - bf2f(h));
            }
#pragma unroll
            for (int ng = 0; ng < 4; ++ng) {
                acc[ng] = __builtin_amdgcn_mfma_f32_16x16x32_bf16(al, bh[ng], acc[ng], 0, 0, 0);
                acc[ng] = __builtin_amdgcn_mfma_f32_16x16x32_bf16(ah, bl[ng], acc[ng], 0, 0, 0);
                acc[ng] = __builtin_amdgcn_mfma_f32_16x16x32_bf16(ah, bh[ng], acc[ng], 0, 0, 0);
            }
        }
    }
#pragma unroll
    for (int ng = 0; ng < 4; ++ng)
#pragma unroll
        for (int r = 0; r < 4; ++r) accs[kg][ng][lane][r] = acc[ng][r];
    __syncthreads();

    // wave (ng = kg&3, r-half = kg>>2) reduces over the 8 K-groups
    {
        const int ng = kg & 3, rh = kg >> 2;
        const int n = ng * 16 + l15;
        const float be = beff[g * 64 + n];
#pragma unroll
        for (int rr = 0; rr < 2; ++rr) {
            const int r = rh * 2 + rr;
            float s = 0.f;
#pragma unroll
            for (int k8 = 0; k8 < 8; ++k8) s += accs[k8][ng][lane][r];
            float v = fmaxf(s + be, 0.f);
            const int il = q * 4 + r;
            hf[(size_t)(g * N + i0 + il) * 64 + n] = v;
            htile[n][il] = f2bf(v);
        }
    }
    __syncthreads();

    if (t < 128) {                                  // emit hfrag (contiguous 16 B per thread)
        const int ng2 = t >> 5, jh = (t >> 4) & 1, l = t & 15;
        uint4 v = *(const uint4*)&htile[ng2 * 16 + l][jh * 8];
        const int jc = i0 >> 6, c = (i0 >> 5) & 1, q0 = (i0 >> 3) & 3;
        const size_t unit = (((size_t)g * 4 + ng2) * 64 + jc) * 2 + c;
        *(uint4*)&hfrag[unit * 512 + (size_t)(q0 + jh) * 128 + l * 8] = v;
    }
}

// ---------------- k2: agg = (adj==1)*alpha @ h; A = prepacked hfrag, B = masked alpha --------
__global__ __launch_bounds__(512, 2) void k2(const int* __restrict__ adj1, const int* __restrict__ adj2,
                                             const float* __restrict__ alpha, const float* __restrict__ Wp,
                                             const unsigned short* __restrict__ hfrag,
                                             const float* __restrict__ hf,
                                             float* __restrict__ outv) {
    const int i0 = blockIdx.x * 16;
    const int t = threadIdx.x;
    const int lane = t & 63, kg = t >> 6;           // 8 waves = 8 K-groups of 512
    const int q = lane >> 4, l15 = lane & 15;

    __shared__ float accs[8][4][64][4];             // 32 KB (reused for graph1 then graph2)
    __shared__ float degp[8][64][2];                // 4 KB
    __shared__ float degf[2][16];

    f32x4 acc1[4], acc2[4];
#pragma unroll
    for (int ng = 0; ng < 4; ++ng) {
        acc1[ng] = (f32x4){0.f, 0.f, 0.f, 0.f};
        acc2[ng] = (f32x4){0.f, 0.f, 0.f, 0.f};
    }
    int deg1 = 0, deg2 = 0;

    const size_t rowoff = (size_t)(i0 + l15) * N;
    for (int kk = 0; kk < 8; ++kk) {
        const int jc = kg * 8 + kk;
#pragma unroll
        for (int c = 0; c < 2; ++c) {
            const int ka = jc * 64 + c * 32 + q * 8;
            const size_t ao = rowoff + ka;
            float4 a0 = *(const float4*)&alpha[ao];
            float4 a1 = *(const float4*)&alpha[ao + 4];
            int4 j10 = *(const int4*)&adj1[ao];
            int4 j11 = *(const int4*)&adj1[ao + 4];
            int4 j20 = *(const int4*)&adj2[ao];
            int4 j21 = *(const int4*)&adj2[ao + 4];
            s16x8 ha1[4], ha2[4];
#pragma unroll
            for (int ng = 0; ng < 4; ++ng) {
                const size_t u1 = (((size_t)0 * 4 + ng) * 64 + jc) * 2 + c;
                const size_t u2 = (((size_t)1 * 4 + ng) * 64 + jc) * 2 + c;
                ha1[ng] = *(const s16x8*)&hfrag[u1 * 512 + lane * 8];
                ha2[ng] = *(const s16x8*)&hfrag[u2 * 512 + lane * 8];
            }
            float av[8] = {a0.x, a0.y, a0.z, a0.w, a1.x, a1.y, a1.z, a1.w};
            int m1[8] = {j10.x == 1, j10.y == 1, j10.z == 1, j10.w == 1,
                         j11.x == 1, j11.y == 1, j11.z == 1, j11.w == 1};
            int m2[8] = {j20.x == 1, j20.y == 1, j20.z == 1, j20.w == 1,
                         j21.x == 1, j21.y == 1, j21.z == 1, j21.w == 1};
            s16x8 bf1, bf2;
#pragma unroll
            for (int j = 0; j < 8; ++j) {
                short bv = (short)f2bf(av[j]);
                bf1[j] = m1[j] ? bv : (short)0;
                bf2[j] = m2[j] ? bv : (short)0;
                deg1 += m1[j];
                deg2 += m2[j];
            }
#pragma unroll
            for (int ng = 0; ng < 4; ++ng) {
                acc1[ng] = __builtin_amdgcn_mfma_f32_16x16x32_bf16(ha1[ng], bf1, acc1[ng], 0, 0, 0);
                acc2[ng] = __builtin_amdgcn_mfma_f32_16x16x32_bf16(ha2[ng], bf2, acc2[ng], 0, 0, 0);
            }
        }
    }

    degp[kg][lane][0] = (float)deg1;
    degp[kg][lane][1] = (float)deg2;
#pragma unroll
    for (int ng = 0; ng < 4; ++ng)
#pragma unroll
        for (int r = 0; r < 4; ++r) accs[kg][ng][lane][r] = acc1[ng][r];
    __syncthreads();
    if (t < 32) {                                   // deg: sum over 8 kg x 4 q slices
        int gg = t >> 4, row = t & 15;
        float s = 0.f;
#pragma unroll
        for (int w = 0; w < 8; ++w)
#pragma unroll
            for (int qq = 0; qq < 4; ++qq) s += degp[w][qq * 16 + row][gg];
        degf[gg][row] = s;
    }
    __syncthreads();

    const float W00 = Wp[0];
    {   // graph 1 epilogue: lane holds (n = ng*16+q*4+r, i = i0+l15)
        const int ng = kg & 3, rh = kg >> 2;
        const int i = i0 + l15;
        const float dg = degf[0][l15];
#pragma unroll
        for (int rr = 0; rr < 2; ++rr) {
            const int r = rh * 2 + rr;
            float s = 0.f;
#pragma unroll
            for (int k8 = 0; k8 < 8; ++k8) s += accs[k8][ng][lane][r];
            const int n = ng * 16 + q * 4 + r;
            float hv = hf[(size_t)i * 64 + n];
            outv[(size_t)i * 64 + n] = (dg != 0.f) ? (s * W00 / fmaxf(dg, 1.f) + hv) : 0.f;
        }
    }
    __syncthreads();                                // done reading accs (graph1)
#pragma unroll
    for (int ng = 0; ng < 4; ++ng)
#pragma unroll
        for (int r = 0; r < 4; ++r) accs[kg][ng][lane][r] = acc2[ng][r];
    __syncthreads();
    {   // graph 2 epilogue
        const int ng = kg & 3, rh = kg >> 2;
        const int i = i0 + l15;
        const float dg = degf[1][l15];
#pragma unroll
        for (int rr = 0; rr < 2; ++rr) {
            const int r = rh * 2 + rr;
            float s = 0.f;
#pragma unroll
            for (int k8 = 0; k8 < 8; ++k8) s += accs[k8][ng][lane][r];
            const int n = ng * 16 + q * 4 + r;
            float hv = hf[(size_t)(N + i) * 64 + n];
            outv[(size_t)(N + i) * 64 + n] = (dg != 0.f) ? (s * W00 / fmaxf(dg, 1.f) + hv) : 0.f;
        }
    }
}

// ---------------- k3a/k3b: out = feat @ clf_w.T + clf_b (two-stage deterministic reduction) ----------------
__global__ __launch_bounds__(256) void k3a(const float* __restrict__ feat, const float* __restrict__ clfw,
                                           float* __restrict__ part) {
    const int t = threadIdx.x;
    const size_t idx = (size_t)blockIdx.x * 2048 + (size_t)t * 8;
    float4 a0 = *(const float4*)&feat[idx];
    float4 a1 = *(const float4*)&feat[idx + 4];
    float4 c0 = *(const float4*)&clfw[idx];
    float4 c1 = *(const float4*)&clfw[idx + 4];
    float4 d0 = *(const float4*)&clfw[524288 + idx];
    float4 d1 = *(const float4*)&clfw[524288 + idx + 4];
    float s0 = a0.x * c0.x + a0.y * c0.y + a0.z * c0.z + a0.w * c0.w
             + a1.x * c1.x + a1.y * c1.y + a1.z * c1.z + a1.w * c1.w;
    float s1 = a0.x * d0.x + a0.y * d0.y + a0.z * d0.z + a0.w * d0.w
             + a1.x * d1.x + a1.y * d1.y + a1.z * d1.z + a1.w * d1.w;
    __shared__ float r0[256], r1[256];
    r0[t] = s0; r1[t] = s1;
    __syncthreads();
    for (int s = 128; s > 0; s >>= 1) {
        if (t < s) { r0[t] += r0[t + s]; r1[t] += r1[t + s]; }
        __syncthreads();
    }
    if (t == 0) { part[blockIdx.x * 2] = r0[0]; part[blockIdx.x * 2 + 1] = r1[0]; }
}

__global__ void k3b(const float* __restrict__ part, const float* __restrict__ clfb,
                    float* __restrict__ outp) {
    const int t = threadIdx.x;
    __shared__ float r0[256], r1[256];
    r0[t] = part[t * 2]; r1[t] = part[t * 2 + 1];
    __syncthreads();
    for (int s = 128; s > 0; s >>= 1) {
        if (t < s) { r0[t] += r0[t + s]; r1[t] += r1[t + s]; }
        __syncthreads();
    }
    if (t == 0) { outp[0] = r0[0] + clfb[0]; outp[1] = r1[0] + clfb[1]; }
}

extern "C" void kernel_launch(void* const* d_in, const int* in_sizes, int n_in,
                              void* d_out, int out_size, void* d_ws, size_t ws_size,
                              hipStream_t stream) {
    const float* x1   = (const float*)d_in[0];
    const float* x2   = (const float*)d_in[1];
    const int*   adj1 = (const int*)d_in[2];
    const int*   adj2 = (const int*)d_in[3];
    const float* e1w1 = (const float*)d_in[4];
    const float* e1b1 = (const float*)d_in[5];
    const float* e1w2 = (const float*)d_in[6];
    const float* e1b2 = (const float*)d_in[7];
    const float* e1w3 = (const float*)d_in[8];
    const float* e1b3 = (const float*)d_in[9];
    const float* e2w1 = (const float*)d_in[10];
    const float* e2b1 = (const float*)d_in[11];
    const float* e2w2 = (const float*)d_in[12];
    const float* e2b2 = (const float*)d_in[13];
    const float* e2w3 = (const float*)d_in[14];
    const float* e2b3 = (const float*)d_in[15];
    const float* Wp   = (const float*)d_in[16];
    const float* alph = (const float*)d_in[17];
    const float* clfw = (const float*)d_in[18];
    const float* clfb = (const float*)d_in[19];

    char* wsb = (char*)d_ws;
    // Wfrag (2 MB) lives through k1; newv (2 MB) aliases it from k2 on.
    unsigned short* Wfrag = (unsigned short*)(wsb);                      // 2 MB
    float* newv = (float*)(wsb);                                         // 2 MB (aliases Wfrag)
    unsigned short* hfrag = (unsigned short*)(wsb + (2u << 20));         // 1 MB
    float* hf   = (float*)(wsb + (3u << 20));                            // 2 MB
    float* T    = (float*)(wsb + (5u << 20));                            // 128 KB
    float* beff = (float*)(wsb + (5u << 20) + (1u << 17));               // 512 B
    float* part = (float*)(wsb + (5u << 20) + (1u << 17) + 4096);        // 2 KB

    hipLaunchKernelGGL(k0a, dim3(64), dim3(256), 0, stream,
                       e1w2, e1w3, e1b1, e1b2, e1b3, e2w2, e2w3, e2b1, e2b2, e2b3, T, beff);
    hipLaunchKernelGGL(k0b, dim3(512), dim3(256), 0, stream, e1w1, e2w1, T, Wfrag);
    hipLaunchKernelGGL(k1, dim3(512), dim3(512), 0, stream, x1, x2, Wfrag, beff, hf, hfrag);
    hipLaunchKernelGGL(k2, dim3(256), dim3(512), 0, stream, adj1, adj2, alph, Wp, hfrag, hf, newv);
    hipLaunchKernelGGL(k3a, dim3(256), dim3(256), 0, stream, newv, clfw, part);
    hipLaunchKernelGGL(k3b, dim3(1), dim3(256), 0, stream, part, clfb, (float*)d_out);
}